// Round 3
// baseline (2943.017 us; speedup 1.0000x reference)
//
#include <hip/hip_runtime.h>

#define N 8192
#define D 512
#define KNEI 10
#define NCAND 16
#define NSPLIT 4
#define BI 64
#define BJ 64
#define BK 32

// ---------------------------------------------------------------------------
// Kernel 0: per-row sq = numpy-pairwise-style fp32 sum of x*x (close to the
// reference's sq to ~1 ulp; the rescore pass is eps-tolerant to this).
// ---------------------------------------------------------------------------
__global__ __launch_bounds__(256) void row_sq_np_kernel(const float* __restrict__ x,
                                                        float* __restrict__ sq) {
  const int wave = threadIdx.x >> 6;
  const int lane = threadIdx.x & 63;
  const int row = blockIdx.x * 4 + wave;
  const float* xr = x + (size_t)row * D;

  float s = 0.f;
  if (lane < 32) {
    const int leaf = lane >> 3;   // 0..3 (blocks of 128)
    const int j = lane & 7;       // stripe
    const float* a = xr + leaf * 128;
    float v = a[j];
    s = __fmul_rn(v, v);
#pragma unroll
    for (int i = 8; i < 128; i += 8) {
      v = a[i + j];
      s = __fadd_rn(s, __fmul_rn(v, v));
    }
  }
  float t1 = __shfl_xor(s, 1);
  s = __fadd_rn(s, t1);
  float t2 = __shfl_xor(s, 2);
  s = __fadd_rn(s, t2);
  float t4 = __shfl_xor(s, 4);
  s = __fadd_rn(s, t4);
  const float L0 = __shfl(s, 0);
  const float L1 = __shfl(s, 8);
  const float L2 = __shfl(s, 16);
  const float L3 = __shfl(s, 24);
  const float total = __fadd_rn(__fadd_rn(L0, L1), __fadd_rn(L2, L3));
  if (lane == 0) sq[row] = total;
}

// ---------------------------------------------------------------------------
// Kernel 1: fused fp32 Gram-GEMM + streaming per-row top-16 filter (unchanged;
// margin to the global rank-10 boundary is ~units vs ~1e-3 filter noise).
// ---------------------------------------------------------------------------
__global__ __launch_bounds__(256) void knn_gemm_kernel(const float* __restrict__ x,
                                                       const float* __restrict__ sq,
                                                       int* __restrict__ cj) {
  __shared__ __align__(16) float As[BI][BK + 4];
  __shared__ __align__(16) float Bs[BJ][BK + 4];
  __shared__ float Cs[BI][BJ + 1];
  __shared__ float sqj_s[BJ];

  const int tid = threadIdx.x;
  const int tx = tid & 15;
  const int ty = tid >> 4;
  const int ibase = blockIdx.x * BI;
  const int jstart = blockIdx.y * (N / NSPLIT);

  float bd[NCAND];
  int bjx[NCAND];
#pragma unroll
  for (int t = 0; t < NCAND; ++t) {
    bd[t] = 3.4e38f;
    bjx[t] = 0;
  }
  const float sqi_own = (tid < BI) ? sq[ibase + tid] : 0.f;

  for (int jt = 0; jt < (N / NSPLIT) / BJ; ++jt) {
    const int jbase = jstart + jt * BJ;
    if (tid < BJ) sqj_s[tid] = sq[jbase + tid];

    float acc[4][4];
#pragma unroll
    for (int i = 0; i < 4; ++i)
#pragma unroll
      for (int j = 0; j < 4; ++j) acc[i][j] = 0.f;

    for (int kt = 0; kt < D / BK; ++kt) {
      const int k0 = kt * BK;
#pragma unroll
      for (int p = 0; p < 2; ++p) {
        const int v = tid + p * 256;
        const int row = v >> 3;
        const int c4 = (v & 7) << 2;
        *(float4*)(&As[row][c4]) =
            *(const float4*)(x + (size_t)(ibase + row) * D + k0 + c4);
        *(float4*)(&Bs[row][c4]) =
            *(const float4*)(x + (size_t)(jbase + row) * D + k0 + c4);
      }
      __syncthreads();
#pragma unroll
      for (int kk = 0; kk < BK; kk += 4) {
        float4 a4[4], b4[4];
#pragma unroll
        for (int i = 0; i < 4; ++i) a4[i] = *(const float4*)(&As[ty + 16 * i][kk]);
#pragma unroll
        for (int j = 0; j < 4; ++j) b4[j] = *(const float4*)(&Bs[tx + 16 * j][kk]);
#pragma unroll
        for (int i = 0; i < 4; ++i)
#pragma unroll
          for (int j = 0; j < 4; ++j)
            acc[i][j] += a4[i].x * b4[j].x + a4[i].y * b4[j].y +
                         a4[i].z * b4[j].z + a4[i].w * b4[j].w;
      }
      __syncthreads();
    }

#pragma unroll
    for (int i = 0; i < 4; ++i)
#pragma unroll
      for (int j = 0; j < 4; ++j) Cs[ty + 16 * i][tx + 16 * j] = acc[i][j];
    __syncthreads();

    if (tid < BI) {
#pragma unroll 1
      for (int c = 0; c < BJ; ++c) {
        const float d = sqi_own - 2.f * Cs[tid][c] + sqj_s[c];
        if (d < bd[NCAND - 1]) {
          float cdv = d;
          int cjv = jbase + c;
#pragma unroll
          for (int t = 0; t < NCAND; ++t) {
            if (cdv < bd[t]) {
              const float td = bd[t];
              const int tj = bjx[t];
              bd[t] = cdv;
              bjx[t] = cjv;
              cdv = td;
              cjv = tj;
            }
          }
        }
      }
    }
    __syncthreads();
  }

  if (tid < BI) {
    const int i = ibase + tid;
#pragma unroll
    for (int t = 0; t < NCAND; ++t)
      cj[((size_t)i * NSPLIT + blockIdx.y) * NCAND + t] = bjx[t];
  }
}

// ---------------------------------------------------------------------------
// Kernel 2: rescore 64 candidates with near-exact z mimicking the reference's
// rounding chain, then top-10 with EPSILON TIE-BREAK preferring LOWER INDEX
// (emulates fp32 d2 quantization ties resolved by stable top_k).
//   G  = fl32(fp64 dot)                      (~= any BLAS's G to ~2 ulp)
//   y  = fl32(sq_i - fl32(2*G))              (ref's intermediate rounding)
//   z  = (double)y + (double)sq_j            (pre-final-rounding value)
//   tie iff |z_a - z_b| <= 1.25e-7 * |z|     (~1.6 ulp of fp32 at |d2|)
// ---------------------------------------------------------------------------
__global__ __launch_bounds__(256) void merge_kernel(const float* __restrict__ x,
                                                    const float* __restrict__ sq,
                                                    const int* __restrict__ cj,
                                                    float* __restrict__ out) {
  __shared__ __align__(16) float xi[D];
  __shared__ double zsh[NSPLIT * NCAND];
  __shared__ int jsh[NSPLIT * NCAND];
  __shared__ int sel[KNEI];

  const int i = blockIdx.x;
  const int tid = threadIdx.x;

  for (int k = tid; k < D; k += 256) xi[k] = x[(size_t)i * D + k];
  if (tid < 64) jsh[tid] = cj[(size_t)i * 64 + tid];
  __syncthreads();

  const float sqi = sq[i];

  // fp64 dot, 4 threads per candidate (128 dims each).
  {
    const int c = tid >> 2;
    const int p = tid & 3;
    const int j = jsh[c];
    const float4* xj4 = (const float4*)(x + (size_t)j * D);
    const float4* xi4 = (const float4*)xi;
    double s = 0.0;
    for (int q = p * (D / 16); q < (p + 1) * (D / 16); ++q) {
      const float4 a = xi4[q];
      const float4 b = xj4[q];
      s += (double)a.x * (double)b.x + (double)a.y * (double)b.y +
           (double)a.z * (double)b.z + (double)a.w * (double)b.w;
    }
    s += __shfl_xor(s, 1);
    s += __shfl_xor(s, 2);
    if (p == 0) {
      const float G = (float)s;
      const float y = __fsub_rn(sqi, __fmul_rn(2.0f, G));
      zsh[c] = (double)y + (double)sq[j];
    }
  }
  __syncthreads();

  // Serial top-10 with eps tie-break (lower index wins within eps).
  if (tid == 0) {
    unsigned long long used = 0ull;
    for (int slot = 0; slot < KNEI; ++slot) {
      int b = -1;
      double zb = 0.0;
      for (int c = 0; c < NSPLIT * NCAND; ++c) {
        if ((used >> c) & 1ull) continue;
        const double zc = zsh[c];
        if (b < 0) {
          b = c;
          zb = zc;
          continue;
        }
        const double eps = 1.25e-7 * fabs(zb);
        bool better;
        if (zc < zb - eps) better = true;
        else if (zc > zb + eps) better = false;
        else better = (jsh[c] < jsh[b]);
        if (better) {
          b = c;
          zb = zc;
        }
      }
      used |= (1ull << b);
      sel[slot] = jsh[b];
    }
  }
  __syncthreads();

  // smoothed = 0.5*x + 0.05 * sum(neighbors)
  for (int k = tid; k < D; k += 256) {
    float a = 0.f;
#pragma unroll
    for (int m = 0; m < KNEI; ++m) a += x[(size_t)sel[m] * D + k];
    out[(size_t)i * D + k] = 0.5f * xi[k] + 0.05f * a;
  }
}

// ---------------------------------------------------------------------------
extern "C" void kernel_launch(void* const* d_in, const int* in_sizes, int n_in,
                              void* d_out, int out_size, void* d_ws, size_t ws_size,
                              hipStream_t stream) {
  const float* x = (const float*)d_in[0];
  float* out = (float*)d_out;
  float* sq = (float*)d_ws;                                   // N floats
  int* cj = (int*)((char*)d_ws + (size_t)N * sizeof(float));  // N*64 ints

  row_sq_np_kernel<<<N / 4, 256, 0, stream>>>(x, sq);
  knn_gemm_kernel<<<dim3(N / BI, NSPLIT), 256, 0, stream>>>(x, sq, cj);
  merge_kernel<<<N, 256, 0, stream>>>(x, sq, cj, out);
}

// Round 4
// 1467.353 us; speedup vs baseline: 2.0057x; 2.0057x over previous
//
#include <hip/hip_runtime.h>

#define N 8192
#define D 512
#define KNEI 10
#define NCAND 16
#define GSPLIT 8
#define TRS 20

typedef __attribute__((ext_vector_type(8))) short bfv8;           // 8 bf16 (4 VGPR)
typedef __attribute__((ext_vector_type(8))) unsigned short usv8;  // 16B chunk
typedef __attribute__((ext_vector_type(4))) float fv4;

// ---------------------------------------------------------------------------
// Kernel 0: per-row fp32 sq (numpy-pairwise-style; eps-tie-break downstream
// tolerates ~ulp differences). Unchanged from round 3 (validated).
// ---------------------------------------------------------------------------
__global__ __launch_bounds__(256) void row_sq_np_kernel(const float* __restrict__ x,
                                                        float* __restrict__ sq) {
  const int wave = threadIdx.x >> 6;
  const int lane = threadIdx.x & 63;
  const int row = blockIdx.x * 4 + wave;
  const float* xr = x + (size_t)row * D;

  float s = 0.f;
  if (lane < 32) {
    const int leaf = lane >> 3;
    const int j = lane & 7;
    const float* a = xr + leaf * 128;
    float v = a[j];
    s = __fmul_rn(v, v);
#pragma unroll
    for (int i = 8; i < 128; i += 8) {
      v = a[i + j];
      s = __fadd_rn(s, __fmul_rn(v, v));
    }
  }
  float t1 = __shfl_xor(s, 1);
  s = __fadd_rn(s, t1);
  float t2 = __shfl_xor(s, 2);
  s = __fadd_rn(s, t2);
  float t4 = __shfl_xor(s, 4);
  s = __fadd_rn(s, t4);
  const float L0 = __shfl(s, 0);
  const float L1 = __shfl(s, 8);
  const float L2 = __shfl(s, 16);
  const float L3 = __shfl(s, 24);
  const float total = __fadd_rn(__fadd_rn(L0, L1), __fadd_rn(L2, L3));
  if (lane == 0) sq[row] = total;
}

// ---------------------------------------------------------------------------
// Kernel 0b: x (fp32) -> xb (bf16, RTNE). 8 elements/thread.
// ---------------------------------------------------------------------------
__device__ inline unsigned short f2bf(float f) {
  unsigned int u = __float_as_uint(f);
  return (unsigned short)((u + 0x7fffu + ((u >> 16) & 1u)) >> 16);
}

__global__ __launch_bounds__(256) void cvt_bf16_kernel(const float* __restrict__ x,
                                                       unsigned short* __restrict__ xb) {
  const int base = (blockIdx.x * 256 + threadIdx.x) * 8;
  const float4 a = *(const float4*)(x + base);
  const float4 b = *(const float4*)(x + base + 4);
  usv8 o;
  o[0] = f2bf(a.x); o[1] = f2bf(a.y); o[2] = f2bf(a.z); o[3] = f2bf(a.w);
  o[4] = f2bf(b.x); o[5] = f2bf(b.y); o[6] = f2bf(b.z); o[7] = f2bf(b.w);
  *(usv8*)(xb + base) = o;
}

// ---------------------------------------------------------------------------
// Kernel 1: MFMA bf16 Gram filter + fused per-row top-16.
// BI=128 rows/block, per-block J-range = N/GSPLIT = 1024 (16 J-tiles of 64),
// BK=64. 4 waves: wave w owns rows w*32..w*32+31 (2 frag-rows) x 64 cols
// (4 frag-cols), 16x16x32 bf16 MFMA, 2 K-halves per BK.
// LDS: Ct fp32 [64][132] (padded), staging As[128][72]/Bs[64][72] bf16
// (stride-72 = bank-spread) ALIASED inside Ct's 33.8 KB. ~34 KB total.
// ---------------------------------------------------------------------------
__global__ __launch_bounds__(256, 2) void knn_gemm_mfma(
    const unsigned short* __restrict__ xb, const float* __restrict__ sq,
    float* __restrict__ cd, int* __restrict__ cjx) {
  __shared__ __align__(16) float Ct[64 * 132];  // 33792 B
  __shared__ float sqj_s[64];

  unsigned short* As = (unsigned short*)Ct;          // 128*72 ushort = 18432 B
  unsigned short* Bs = (unsigned short*)Ct + 9216;   // 64*72 ushort  =  9216 B

  const int tid = threadIdx.x;
  const int lane = tid & 63;
  const int wave = tid >> 6;
  const int m = lane & 15;
  const int kg = lane >> 4;  // 0..3
  const int ibase = blockIdx.x * 128;
  const int jstart = blockIdx.y * (N / GSPLIT);

  // Staging decomposition (16B chunks): row = ci>>3, ko = (ci&7)*8 bf16.
  const int strow = tid >> 3;
  const int stko = (tid & 7) * 8;

  float bd[NCAND];
  int bjv[NCAND];
#pragma unroll
  for (int t = 0; t < NCAND; ++t) {
    bd[t] = 3.4e38f;
    bjv[t] = 0;
  }
  const float sqi_own = (tid < 128) ? sq[ibase + tid] : 0.f;

  for (int jt = 0; jt < 16; ++jt) {
    const int jbase = jstart + jt * 64;
    if (tid < 64) sqj_s[tid] = sq[jbase + tid];

    fv4 acc[2][4];
#pragma unroll
    for (int fi = 0; fi < 2; ++fi)
#pragma unroll
      for (int fj = 0; fj < 4; ++fj) acc[fi][fj] = (fv4)(0.f);

    for (int kt = 0; kt < D / 64; ++kt) {
      const int k0 = kt * 64;
      __syncthreads();  // prior-phase reads of Ct/As/Bs complete
      // Stage A: 128x64 bf16 = 1024 chunks (4/thread); B: 64x64 = 512 (2/thread)
#pragma unroll
      for (int q = 0; q < 4; ++q) {
        const int row = strow + q * 32;
        *(usv8*)(As + row * 72 + stko) =
            *(const usv8*)(xb + (size_t)(ibase + row) * D + k0 + stko);
      }
#pragma unroll
      for (int q = 0; q < 2; ++q) {
        const int row = strow + q * 32;
        if (row < 64)
          *(usv8*)(Bs + row * 72 + stko) =
              *(const usv8*)(xb + (size_t)(jbase + row) * D + k0 + stko);
      }
      __syncthreads();

      bfv8 af[2][2], bfr[4][2];
#pragma unroll
      for (int fi = 0; fi < 2; ++fi)
#pragma unroll
        for (int kh = 0; kh < 2; ++kh)
          af[fi][kh] = *(const bfv8*)(As + (wave * 32 + fi * 16 + m) * 72 +
                                      kh * 32 + kg * 8);
#pragma unroll
      for (int fj = 0; fj < 4; ++fj)
#pragma unroll
        for (int kh = 0; kh < 2; ++kh)
          bfr[fj][kh] = *(const bfv8*)(Bs + (fj * 16 + m) * 72 + kh * 32 + kg * 8);

#pragma unroll
      for (int fi = 0; fi < 2; ++fi)
#pragma unroll
        for (int fj = 0; fj < 4; ++fj) {
          acc[fi][fj] = __builtin_amdgcn_mfma_f32_16x16x32_bf16(
              af[fi][0], bfr[fj][0], acc[fi][fj], 0, 0, 0);
          acc[fi][fj] = __builtin_amdgcn_mfma_f32_16x16x32_bf16(
              af[fi][1], bfr[fj][1], acc[fi][fj], 0, 0, 0);
        }
    }
    __syncthreads();  // all frag reads done; Ct may overwrite staging

    // Dump transposed: C/D layout col=lane&15, row=(lane>>4)*4+reg.
#pragma unroll
    for (int fi = 0; fi < 2; ++fi)
#pragma unroll
      for (int fj = 0; fj < 4; ++fj) {
        const int col = fj * 16 + m;
        const int row0 = wave * 32 + fi * 16 + kg * 4;
        *(fv4*)(&Ct[col * 132 + row0]) = acc[fi][fj];
      }
    __syncthreads();

    // Selection: threads 0..127 = one i-row each, scan 64 cols.
    if (tid < 128) {
#pragma unroll 2
      for (int c = 0; c < 64; ++c) {
        const float d = sqi_own - 2.f * Ct[c * 132 + tid] + sqj_s[c];
        if (d < bd[NCAND - 1]) {
          float cdv = d;
          int cjv = jbase + c;
#pragma unroll
          for (int t = 0; t < NCAND; ++t) {
            if (cdv < bd[t]) {
              const float td = bd[t];
              const int tj = bjv[t];
              bd[t] = cdv;
              bjv[t] = cjv;
              cdv = td;
              cjv = tj;
            }
          }
        }
      }
    }
    __syncthreads();  // selection reads done before next jt staging/sqj write
  }

  if (tid < 128) {
    const int i = ibase + tid;
    const size_t base = ((size_t)i * GSPLIT + blockIdx.y) * NCAND;
#pragma unroll
    for (int t = 0; t < NCAND; ++t) {
      cd[base + t] = bd[t];
      cjx[base + t] = bjv[t];
    }
  }
}

// ---------------------------------------------------------------------------
// Kernel 2: per-row merge. (1) noisy top-20 pre-select from 128 candidates
// (wave-0 butterfly, 2 cands/lane); (2) fp64 rescore of those 20 with the
// reference's fp32 rounding chain; (3) serial top-10 with eps tie-break
// (lower index within 1.25e-7 rel — validated round 3); (4) smoothing.
// ---------------------------------------------------------------------------
__global__ __launch_bounds__(256) void merge_kernel(const float* __restrict__ x,
                                                    const float* __restrict__ sq,
                                                    const float* __restrict__ cd,
                                                    const int* __restrict__ cjx,
                                                    float* __restrict__ out) {
  __shared__ __align__(16) float xi[D];
  __shared__ float csc[128];
  __shared__ int cix[128];
  __shared__ int selc[TRS];
  __shared__ double zsh[TRS];
  __shared__ int sel[KNEI];

  const int i = blockIdx.x;
  const int tid = threadIdx.x;

  for (int k = tid; k < D; k += 256) xi[k] = x[(size_t)i * D + k];
  if (tid < 128) {
    csc[tid] = cd[(size_t)i * 128 + tid];
    cix[tid] = cjx[(size_t)i * 128 + tid];
  }
  __syncthreads();

  // (1) noisy top-20 superset
  if (tid < 64) {
    float s0 = csc[tid], s1 = csc[tid + 64];
    const int j0 = cix[tid], j1 = cix[tid + 64];
    for (int slot = 0; slot < TRS; ++slot) {
      float bm;
      int bj;
      if (s0 <= s1) { bm = s0; bj = j0; } else { bm = s1; bj = j1; }
#pragma unroll
      for (int off = 32; off; off >>= 1) {
        const float om = __shfl_xor(bm, off);
        const int oj = __shfl_xor(bj, off);
        if (om < bm || (om == bm && oj < bj)) { bm = om; bj = oj; }
      }
      if (tid == 0) selc[slot] = bj;
      if (j0 == bj) s0 = 3.4e38f;
      if (j1 == bj) s1 = 3.4e38f;
    }
  }
  __syncthreads();

  const float sqi = sq[i];

  // (2) exact rescore: 8 threads per candidate, 64 dims each.
  if (tid < 8 * TRS) {
    const int c = tid >> 3;
    const int p = tid & 7;
    const int j = selc[c];
    const float4* xj4 = (const float4*)(x + (size_t)j * D);
    const float4* xi4 = (const float4*)xi;
    double s = 0.0;
    for (int q = p * 16; q < p * 16 + 16; ++q) {
      const float4 a = xi4[q];
      const float4 b = xj4[q];
      s += (double)a.x * (double)b.x + (double)a.y * (double)b.y +
           (double)a.z * (double)b.z + (double)a.w * (double)b.w;
    }
    s += __shfl_xor(s, 1);
    s += __shfl_xor(s, 2);
    s += __shfl_xor(s, 4);
    if (p == 0) {
      const float G = (float)s;
      const float y = __fsub_rn(sqi, __fmul_rn(2.0f, G));
      zsh[c] = (double)y + (double)sq[j];
    }
  }
  __syncthreads();

  // (3) serial top-10 with eps tie-break (lower index wins within eps).
  if (tid == 0) {
    unsigned int used = 0u;
    for (int slot = 0; slot < KNEI; ++slot) {
      int b = -1;
      double zb = 0.0;
      for (int c = 0; c < TRS; ++c) {
        if ((used >> c) & 1u) continue;
        const double zc = zsh[c];
        if (b < 0) {
          b = c;
          zb = zc;
          continue;
        }
        const double eps = 1.25e-7 * fabs(zb);
        bool better;
        if (zc < zb - eps) better = true;
        else if (zc > zb + eps) better = false;
        else better = (selc[c] < selc[b]);
        if (better) {
          b = c;
          zb = zc;
        }
      }
      used |= (1u << b);
      sel[slot] = selc[b];
    }
  }
  __syncthreads();

  // (4) smoothed = 0.5*x + 0.05 * sum(neighbors)
  for (int k = tid; k < D; k += 256) {
    float a = 0.f;
#pragma unroll
    for (int mth = 0; mth < KNEI; ++mth) a += x[(size_t)sel[mth] * D + k];
    out[(size_t)i * D + k] = 0.5f * xi[k] + 0.05f * a;
  }
}

// ---------------------------------------------------------------------------
extern "C" void kernel_launch(void* const* d_in, const int* in_sizes, int n_in,
                              void* d_out, int out_size, void* d_ws, size_t ws_size,
                              hipStream_t stream) {
  const float* x = (const float*)d_in[0];
  float* out = (float*)d_out;

  char* ws = (char*)d_ws;
  float* sq = (float*)ws;                                   // 32 KB
  unsigned short* xb = (unsigned short*)(ws + 32768);       // 8 MB
  float* cd = (float*)(ws + 32768 + 8388608);               // 4 MB
  int* cjx = (int*)(ws + 32768 + 8388608 + 4194304);        // 4 MB

  row_sq_np_kernel<<<N / 4, 256, 0, stream>>>(x, sq);
  cvt_bf16_kernel<<<(N * D) / (8 * 256), 256, 0, stream>>>(x, xb);
  knn_gemm_mfma<<<dim3(N / 128, GSPLIT), 256, 0, stream>>>(xb, sq, cd, cjx);
  merge_kernel<<<N, 256, 0, stream>>>(x, sq, cd, cjx, out);
}

// Round 5
// 319.038 us; speedup vs baseline: 9.2247x; 4.5993x over previous
//
#include <hip/hip_runtime.h>

#define N 8192
#define D 512
#define KNEI 10
#define NC 8           // keys kept per (row, col-half) per split
#define GSPLIT 16
#define TRS 20
#define NTOT (GSPLIT * 2 * NC)  // 256 candidates per row

typedef __attribute__((ext_vector_type(8))) short bfv8;           // 8 bf16
typedef __attribute__((ext_vector_type(8))) unsigned short usv8;  // 16B
typedef __attribute__((ext_vector_type(4))) float fv4;
typedef unsigned int uint32;

#define GLOAD_LDS16(gp, lp)                                                  \
  __builtin_amdgcn_global_load_lds(                                          \
      (const __attribute__((address_space(1))) void*)(gp),                   \
      (__attribute__((address_space(3))) void*)(lp), 16, 0, 0)

__device__ inline unsigned short f2bf(float f) {
  unsigned int u = __float_as_uint(f);
  return (unsigned short)((u + 0x7fffu + ((u >> 16) & 1u)) >> 16);
}

// ---------------------------------------------------------------------------
// Kernel 0: per-row fp32 sq (numpy-pairwise-style; validated round 3/4).
// ---------------------------------------------------------------------------
__global__ __launch_bounds__(256) void row_sq_np_kernel(const float* __restrict__ x,
                                                        float* __restrict__ sq) {
  const int wave = threadIdx.x >> 6;
  const int lane = threadIdx.x & 63;
  const int row = blockIdx.x * 4 + wave;
  const float* xr = x + (size_t)row * D;

  float s = 0.f;
  if (lane < 32) {
    const int leaf = lane >> 3;
    const int j = lane & 7;
    const float* a = xr + leaf * 128;
    float v = a[j];
    s = __fmul_rn(v, v);
#pragma unroll
    for (int i = 8; i < 128; i += 8) {
      v = a[i + j];
      s = __fadd_rn(s, __fmul_rn(v, v));
    }
  }
  float t1 = __shfl_xor(s, 1);
  s = __fadd_rn(s, t1);
  float t2 = __shfl_xor(s, 2);
  s = __fadd_rn(s, t2);
  float t4 = __shfl_xor(s, 4);
  s = __fadd_rn(s, t4);
  const float L0 = __shfl(s, 0);
  const float L1 = __shfl(s, 8);
  const float L2 = __shfl(s, 16);
  const float L3 = __shfl(s, 24);
  const float total = __fadd_rn(__fadd_rn(L0, L1), __fadd_rn(L2, L3));
  if (lane == 0) sq[row] = total;
}

// ---------------------------------------------------------------------------
// Kernel 0b: fp32 -> bf16 (RTNE).
// ---------------------------------------------------------------------------
__global__ __launch_bounds__(256) void cvt_bf16_kernel(const float* __restrict__ x,
                                                       unsigned short* __restrict__ xb) {
  const int base = (blockIdx.x * 256 + threadIdx.x) * 8;
  const float4 a = *(const float4*)(x + base);
  const float4 b = *(const float4*)(x + base + 4);
  usv8 o;
  o[0] = f2bf(a.x); o[1] = f2bf(a.y); o[2] = f2bf(a.z); o[3] = f2bf(a.w);
  o[4] = f2bf(b.x); o[5] = f2bf(b.y); o[6] = f2bf(b.z); o[7] = f2bf(b.w);
  *(usv8*)(xb + base) = o;
}

// ---------------------------------------------------------------------------
// Kernel 1: MFMA bf16 Gram + fused selection.
// Grid (64, 16): 128 i-rows x 512 j-range per block, 8 j-tiles of 64, BK=64.
// Staging: global_load_lds width=16, unpadded stride-64 rows, chunk index
// XOR-swizzled by (row&7) so frag ds_read_b128 hits the 8-clock floor.
// Selection: all 256 threads (row = tid&127, col-half = tid>>7), 8-deep chain
// on packed keys (bf16(d)<<16 | j).
// ---------------------------------------------------------------------------
__global__ __launch_bounds__(256, 4) void knn_gemm_mfma(
    const unsigned short* __restrict__ xb, const float* __restrict__ sq,
    uint32* __restrict__ ck) {
  __shared__ __align__(16) float Ct[64 * 136];  // 34816 B
  __shared__ float sqj_s[64];
  unsigned short* As = (unsigned short*)Ct;            // 128x64 bf16 = 16384 B
  unsigned short* Bs = (unsigned short*)Ct + 128 * 64; // 64x64 bf16 =  8192 B

  const int tid = threadIdx.x;
  const int lane = tid & 63;
  const int wave = tid >> 6;
  const int m = lane & 15;
  const int kg = lane >> 4;
  const int ibase = blockIdx.x * 128;
  const int jstart = blockIdx.y * (N / GSPLIT);

  const int srow = lane >> 3;   // staging: row within 8-row wave chunk
  const int schunk = lane & 7;  // staging: 16B chunk within row
  const int sko = (schunk ^ srow) * 8;  // XOR-swizzled source k-offset

  uint32 bk[NC];
#pragma unroll
  for (int t = 0; t < NC; ++t) bk[t] = 0xffffffffu;

  const int selrow = tid & 127;
  const int selhalf = tid >> 7;
  const float sqi_own = sq[ibase + selrow];

  for (int jt = 0; jt < 8; ++jt) {
    const int jbase = jstart + jt * 64;

    fv4 acc[2][4];
#pragma unroll
    for (int fi = 0; fi < 2; ++fi)
#pragma unroll
      for (int fj = 0; fj < 4; ++fj) acc[fi][fj] = (fv4)(0.f);

    for (int kt = 0; kt < 8; ++kt) {
      const int k0 = kt * 64;
      __syncthreads();  // prior frag/Ct/sqj reads done; LDS reusable
      if (kt == 0 && tid < 64) sqj_s[tid] = sq[jbase + tid];
      // A: wave stages rows wave*8 + q*32 .. +7 (4 chunks of 8 rows)
#pragma unroll
      for (int q = 0; q < 4; ++q) {
        const int rbase = wave * 8 + q * 32;
        const unsigned short* gp =
            xb + (size_t)(ibase + rbase + srow) * D + k0 + sko;
        GLOAD_LDS16(gp, As + rbase * 64);
      }
#pragma unroll
      for (int q = 0; q < 2; ++q) {
        const int rbase = wave * 8 + q * 32;
        const unsigned short* gp =
            xb + (size_t)(jbase + rbase + srow) * D + k0 + sko;
        GLOAD_LDS16(gp, Bs + rbase * 64);
      }
      __syncthreads();  // staging visible (vmcnt drained at barrier)

      bfv8 af[2][2];
#pragma unroll
      for (int fi = 0; fi < 2; ++fi) {
        const int row = wave * 32 + fi * 16 + m;
#pragma unroll
        for (int kh = 0; kh < 2; ++kh) {
          const int ch = (kh * 4 + kg) ^ (row & 7);
          af[fi][kh] = *(const bfv8*)(As + row * 64 + ch * 8);
        }
      }
#pragma unroll
      for (int fj = 0; fj < 4; ++fj) {
        const int row = fj * 16 + m;
        const bfv8 b0 = *(const bfv8*)(Bs + row * 64 + ((kg ^ (row & 7)) * 8));
        const bfv8 b1 =
            *(const bfv8*)(Bs + row * 64 + (((4 + kg) ^ (row & 7)) * 8));
#pragma unroll
        for (int fi = 0; fi < 2; ++fi) {
          acc[fi][fj] = __builtin_amdgcn_mfma_f32_16x16x32_bf16(
              af[fi][0], b0, acc[fi][fj], 0, 0, 0);
          acc[fi][fj] = __builtin_amdgcn_mfma_f32_16x16x32_bf16(
              af[fi][1], b1, acc[fi][fj], 0, 0, 0);
        }
      }
    }
    __syncthreads();  // frag reads done; Ct may overwrite staging

    // Transpose to Ct (C/D layout: col=lane&15, row=(lane>>4)*4+reg).
#pragma unroll
    for (int fi = 0; fi < 2; ++fi)
#pragma unroll
      for (int fj = 0; fj < 4; ++fj)
        *(fv4*)(&Ct[(fj * 16 + m) * 136 + wave * 32 + fi * 16 + kg * 4]) =
            acc[fi][fj];
    __syncthreads();

    // Selection: all 4 waves; thread = (row, col-half), 32 cols each.
    const int cbase = selhalf * 32;
#pragma unroll 1
    for (int cc = 0; cc < 32; ++cc) {
      const int c = cbase + cc;
      const float d =
          fmaxf(sqi_own - 2.f * Ct[c * 136 + selrow] + sqj_s[c], 0.f);
      const uint32 key = ((uint32)f2bf(d) << 16) | (uint32)(jbase + c);
      if (key < bk[NC - 1]) {
        uint32 kv = key;
#pragma unroll
        for (int t = 0; t < NC; ++t) {
          if (kv < bk[t]) {
            const uint32 tmp = bk[t];
            bk[t] = kv;
            kv = tmp;
          }
        }
      }
    }
    // next jt's first barrier protects Ct/sqj_s until all reads done
  }

  const size_t obase =
      ((size_t)(ibase + selrow) * (GSPLIT * 2) + blockIdx.y * 2 + selhalf) * NC;
#pragma unroll
  for (int t = 0; t < NC; ++t) ck[obase + t] = bk[t];
}

// ---------------------------------------------------------------------------
// Kernel 2: per-row merge. Preselect top-20 of 256 packed keys (wave-0
// butterfly, 4/lane), fp64 rescore with the reference's fp32 rounding chain,
// serial top-10 with eps tie-break (validated round 3/4), smoothing.
// ---------------------------------------------------------------------------
__global__ __launch_bounds__(256) void merge_kernel(const float* __restrict__ x,
                                                    const float* __restrict__ sq,
                                                    const uint32* __restrict__ ck,
                                                    float* __restrict__ out) {
  __shared__ __align__(16) float xi[D];
  __shared__ uint32 keys[NTOT];
  __shared__ int selc[TRS];
  __shared__ double zsh[TRS];
  __shared__ int sel[KNEI];

  const int i = blockIdx.x;
  const int tid = threadIdx.x;

  for (int k = tid; k < D; k += 256) xi[k] = x[(size_t)i * D + k];
  if (tid < NTOT) keys[tid] = ck[(size_t)i * NTOT + tid];
  __syncthreads();

  // (1) top-20 by packed key (bf16 score, then lower index — keys unique)
  if (tid < 64) {
    uint32 l0 = keys[tid], l1 = keys[tid + 64], l2 = keys[tid + 128],
           l3 = keys[tid + 192];
    for (int slot = 0; slot < TRS; ++slot) {
      uint32 r = min(min(l0, l1), min(l2, l3));
#pragma unroll
      for (int off = 32; off; off >>= 1) {
        const uint32 o = __shfl_xor(r, off);
        r = min(r, o);
      }
      if (tid == 0) selc[slot] = (int)(r & 0xffffu);
      if (l0 == r) l0 = 0xffffffffu;
      if (l1 == r) l1 = 0xffffffffu;
      if (l2 == r) l2 = 0xffffffffu;
      if (l3 == r) l3 = 0xffffffffu;
    }
  }
  __syncthreads();

  const float sqi = sq[i];

  // (2) fp64 rescore, 8 threads per candidate.
  if (tid < 8 * TRS) {
    const int c = tid >> 3;
    const int p = tid & 7;
    const int j = selc[c];
    const float4* xj4 = (const float4*)(x + (size_t)j * D);
    const float4* xi4 = (const float4*)xi;
    double s = 0.0;
    for (int q = p * 16; q < p * 16 + 16; ++q) {
      const float4 a = xi4[q];
      const float4 b = xj4[q];
      s += (double)a.x * (double)b.x + (double)a.y * (double)b.y +
           (double)a.z * (double)b.z + (double)a.w * (double)b.w;
    }
    s += __shfl_xor(s, 1);
    s += __shfl_xor(s, 2);
    s += __shfl_xor(s, 4);
    if (p == 0) {
      const float G = (float)s;
      const float y = __fsub_rn(sqi, __fmul_rn(2.0f, G));
      zsh[c] = (double)y + (double)sq[j];
    }
  }
  __syncthreads();

  // (3) serial top-10, eps tie-break (lower index within 1.25e-7 rel).
  if (tid == 0) {
    unsigned int used = 0u;
    for (int slot = 0; slot < KNEI; ++slot) {
      int b = -1;
      double zb = 0.0;
      for (int c = 0; c < TRS; ++c) {
        if ((used >> c) & 1u) continue;
        const double zc = zsh[c];
        if (b < 0) {
          b = c;
          zb = zc;
          continue;
        }
        const double eps = 1.25e-7 * fabs(zb);
        bool better;
        if (zc < zb - eps) better = true;
        else if (zc > zb + eps) better = false;
        else better = (selc[c] < selc[b]);
        if (better) {
          b = c;
          zb = zc;
        }
      }
      used |= (1u << b);
      sel[slot] = selc[b];
    }
  }
  __syncthreads();

  // (4) smoothed = 0.5*x + 0.05 * sum(neighbors)
  for (int k = tid; k < D; k += 256) {
    float a = 0.f;
#pragma unroll
    for (int mth = 0; mth < KNEI; ++mth) a += x[(size_t)sel[mth] * D + k];
    out[(size_t)i * D + k] = 0.5f * xi[k] + 0.05f * a;
  }
}

// ---------------------------------------------------------------------------
extern "C" void kernel_launch(void* const* d_in, const int* in_sizes, int n_in,
                              void* d_out, int out_size, void* d_ws, size_t ws_size,
                              hipStream_t stream) {
  const float* x = (const float*)d_in[0];
  float* out = (float*)d_out;

  char* ws = (char*)d_ws;
  float* sq = (float*)ws;                              // 32 KB
  unsigned short* xb = (unsigned short*)(ws + 32768);  // 8 MB
  uint32* ck = (uint32*)(ws + 32768 + 8388608);        // 8 MB

  row_sq_np_kernel<<<N / 4, 256, 0, stream>>>(x, sq);
  cvt_bf16_kernel<<<(N * D) / (8 * 256), 256, 0, stream>>>(x, xb);
  knn_gemm_mfma<<<dim3(N / 128, GSPLIT), 256, 0, stream>>>(xb, sq, ck);
  merge_kernel<<<N, 256, 0, stream>>>(x, sq, ck, out);
}